// Round 14
// baseline (380.500 us; speedup 1.0000x reference)
//
#include <hip/hip_runtime.h>
#include <hip/hip_bf16.h>

// HGNNP_GCN + ClusterNet forward, MI355X (round 14).
// R13 counters: k_cluster_accum 42us at 6.5% occupancy (serial 128-row LDS
// loop, 40KB LDS, 391x2-wave grid) -> latency-bound structure. This round:
// clustering restructured to streaming form. k_cluster_iter: softmax row-per-
// thread from global + wave-per-cluster outer-product partials (no contended
// atomics); k_creduce tree-sums partials; k_cluster_final row-per-thread,
// 2.5KB LDS. csum memset deleted.

#define NN   50000   // nodes (= 250*200 = 200*250)
#define NP   50048   // padded rows (782 * 64)
#define EE   800000  // directed edges (= 128*6250)
#define NINC 200000  // incidence entries (= 64*3125)
#define NEH  10000   // hyperedges (= 250*40)
#define KCL  10      // clusters

// output element offsets (flat concat: mu | r | embeds | dist)
#define MU_OFF  0
#define R_OFF   640
#define EMB_OFF 500640
#define D_OFF   3700640

typedef __hip_bfloat16 bf16;
typedef unsigned short u16;
typedef unsigned int   u32;
typedef __attribute__((ext_vector_type(8))) short short8;
typedef __attribute__((ext_vector_type(4))) float f32x4;

__device__ __forceinline__ float b2f(bf16 v){ return __bfloat162float(v); }
__device__ __forceinline__ float us2f(u16 u){ return __uint_as_float(((unsigned)u) << 16); }
__device__ __forceinline__ u16 f2bu(float f){
  unsigned u = __float_as_uint(f);
  return (u16)((u + 0x7fffu + ((u >> 16) & 1u)) >> 16);   // RNE
}
__device__ __forceinline__ bf16 f2b(float f){
  u16 r = f2bu(f);
  bf16 h;
  reinterpret_cast<u16&>(h) = r;
  return h;
}
__device__ __forceinline__ float ldf(const void* p, size_t i, int isbf){
  return isbf ? b2f(((const bf16*)p)[i]) : ((const float*)p)[i];
}
__device__ __forceinline__ void stf(void* p, size_t i, float v, int isbf){
  if (isbf) ((bf16*)p)[i] = f2b(v);
  else      ((float*)p)[i] = v;
}

// ---------------- dtype detector ----------------
__global__ void k_detect(const u16* __restrict__ xr, int* flag){
  __shared__ int bad;
  if (threadIdx.x == 0) bad = 0;
  __syncthreads();
  for (int i = threadIdx.x; i < 4096; i += 256){
    int e = (xr[i] >> 7) & 0xFF;
    if (e >= 0xEF) bad = 1;     // f32 low-halves have random exponents
  }
  __syncthreads();
  if (threadIdx.x == 0) *flag = bad ? 0 : 1;   // 1 = bf16, 0 = f32
}

// ---------------- input prep ----------------
__global__ void k_aconv(const void* __restrict__ x, u16* __restrict__ xb,
                        const int* __restrict__ flag){
  int i = blockIdx.x*256 + threadIdx.x;      // one ushort4 (4 elems)
  const int n4 = NN*256/4;
  if (i >= n4) return;
  ushort4 o;
  if (flag[0]){
    o = ((const ushort4*)x)[i];
  } else {
    float4 v = ((const float4*)x)[i];
    o = make_ushort4(f2bu(v.x), f2bu(v.y), f2bu(v.z), f2bu(v.w));
  }
  ((ushort4*)xb)[i] = o;
}

__global__ void k_wprep(const void* gW1, const void* hW1, const void* gW2, const void* hW2,
                        const void* gb1, const void* hb1, const void* gb2, const void* hb2,
                        u16* gW1t, u16* hW1t, u16* gW2t, u16* hW2t,
                        float* gb1f, float* hb1f, float* gb2f, float* hb2f,
                        const int* __restrict__ flag){
  const int isbf = flag[0];
  int i = blockIdx.x*256 + threadIdx.x;
  if (i < 256*128){                    // Wt[n][k] = W[k][n], 128x256
    int n = i >> 8, k = i & 255;
    gW1t[i] = f2bu(ldf(gW1, (size_t)k*128 + n, isbf));
    hW1t[i] = f2bu(ldf(hW1, (size_t)k*128 + n, isbf));
  }
  if (i < 64*128){                     // 64x128
    int n = i >> 7, k = i & 127;
    gW2t[i] = f2bu(ldf(gW2, (size_t)k*64 + n, isbf));
    hW2t[i] = f2bu(ldf(hW2, (size_t)k*64 + n, isbf));
  }
  if (i < 128){ gb1f[i] = ldf(gb1,i,isbf); hb1f[i] = ldf(hb1,i,isbf); }
  if (i < 64) { gb2f[i] = ldf(gb2,i,isbf); hb2f[i] = ldf(hb2,i,isbf); }
}

// ---------------- two-pass bucket CSR build ----------------
template<int NBKT, int NPB>
__global__ __launch_bounds__(256) void k_histA(const int* __restrict__ key,
                                               int* __restrict__ HA, int chunk){
  __shared__ u32 hist[NBKT];
  for (int i = threadIdx.x; i < NBKT; i += 256) hist[i] = 0;
  __syncthreads();
  int base = blockIdx.x*chunk;
  for (int i = threadIdx.x; i < chunk; i += 256)
    atomicAdd(&hist[key[base+i]/NPB], 1u);
  __syncthreads();
  int* out = HA + blockIdx.x*NBKT;
  for (int i = threadIdx.x; i < NBKT; i += 256) out[i] = (int)hist[i];
}

// per-bucket prefix over chunks (in place) + bucket starts bs[0..250]
__global__ void k_scanA_all(int* HAg, int* HAv, int* HAe,
                            int* bsg, int* bsv, int* bse){
  int* HA; int* bs; int nch;
  if (blockIdx.x == 0){ HA = HAg; bs = bsg; nch = 128; }
  else if (blockIdx.x == 1){ HA = HAv; bs = bsv; nch = 64; }
  else { HA = HAe; bs = bse; nch = 64; }
  __shared__ int s[256];
  int t = threadIdx.x;
  int run = 0;
  if (t < 250){
    for (int c = 0; c < nch; ++c){
      int v = HA[c*250 + t];
      HA[c*250 + t] = run;       // prefix-before-chunk
      run += v;
    }
  }
  int own = (t < 250) ? run : 0;
  s[t] = own; __syncthreads();
  #pragma unroll
  for (int off = 1; off < 256; off <<= 1){
    int add = (t >= off) ? s[t-off] : 0;
    __syncthreads();
    s[t] += add;
    __syncthreads();
  }
  if (t < 250) bs[t] = s[t] - own;   // exclusive bucket start
  if (t == 255) bs[250] = s[255];    // total
}

// Pass A fill: partition into buckets as packed u32 (lk<<16 | val).
template<int NBKT, int NPB>
__global__ __launch_bounds__(256) void k_fillA(const int* __restrict__ key,
    const int* __restrict__ val, const int* __restrict__ HA,
    const int* __restrict__ bs, u32* __restrict__ packed, int chunk){
  __shared__ u32 cur[NBKT];
  const int* pre = HA + blockIdx.x*NBKT;
  for (int i = threadIdx.x; i < NBKT; i += 256) cur[i] = (u32)(bs[i] + pre[i]);
  __syncthreads();
  int base = blockIdx.x*chunk;
  for (int i = threadIdx.x; i < chunk; i += 256){
    int k = key[base+i];
    int b = k / NPB;
    u32 pos = atomicAdd(&cur[b], 1u);
    packed[pos] = ((u32)(k - b*NPB) << 16) | (u32)val[base+i];
  }
}

// Pass B: one block per bucket; csr scatter in a private window.
template<int NPB>
__global__ __launch_bounds__(256) void k_fillB(const u32* __restrict__ packed,
    const int* __restrict__ bs, int* __restrict__ csr,
    int* __restrict__ cnt, int* __restrict__ rp){
  __shared__ u32 hist[NPB];
  __shared__ int s[256];
  __shared__ u32 cur[NPB];
  const int b = blockIdx.x;
  const int s0 = bs[b], m = bs[b+1] - s0;
  const int t = threadIdx.x;
  for (int i = t; i < NPB; i += 256) hist[i] = 0;
  __syncthreads();
  for (int i = t; i < m; i += 256)
    atomicAdd(&hist[packed[s0+i] >> 16], 1u);
  __syncthreads();
  int own = (t < NPB) ? (int)hist[t] : 0;
  s[t] = own; __syncthreads();
  #pragma unroll
  for (int off = 1; off < 256; off <<= 1){
    int add = (t >= off) ? s[t-off] : 0;
    __syncthreads();
    s[t] += add;
    __syncthreads();
  }
  if (t < NPB){
    int excl = s[t] - own;
    cnt[b*NPB + t] = own;
    rp[b*NPB + t]  = s0 + excl;
    cur[t] = (u32)(s0 + excl);
  }
  __syncthreads();
  for (int i = t; i < m; i += 256){
    u32 p = packed[s0+i];
    u32 pos = atomicAdd(&cur[p >> 16], 1u);
    csr[pos] = (int)(p & 0xffffu);
  }
}

__global__ void k_invs(const int* __restrict__ cg, const int* __restrict__ cv,
                       const int* __restrict__ ce,
                       float* dinv, float* invv, float* inve){
  int i = blockIdx.x*256 + threadIdx.x;
  if (i < NN){
    float d = 1.0f + (float)cg[i];     // self-loop included
    dinv[i] = rsqrtf(d);
    invv[i] = 1.0f / fmaxf((float)cv[i], 1.0f);
  } else if (i < NP){
    dinv[i] = 0.f;                     // pad rows
  }
  if (i < NEH) inve[i] = 1.0f / fmaxf((float)ce[i], 1.0f);
}

// ---------------- MFMA GEMM ----------------
template<int KDIM, int NCOL>
__global__ __launch_bounds__(256) void k_gemm_mfma(
    const u16* __restrict__ A, const u16* __restrict__ Wt,
    const float* __restrict__ bias, const float* __restrict__ rowscale,
    u16* __restrict__ C, int relu)
{
  constexpr int NT  = NCOL/16;
  constexpr int LDA = 40;
  __shared__ __align__(16) u16 Asl[64][LDA];
  __shared__ __align__(16) u16 Wsl[NCOL][LDA];
  const int tid  = threadIdx.x;
  const int wave = tid >> 6, lane = tid & 63;
  const int l15 = lane & 15, l4 = lane >> 4;
  const int row0 = blockIdx.x * 64;
  const int ar = tid >> 2, aq = tid & 3;
  constexpr int NW = NCOL*4/256;

  f32x4 acc[NT] = {};

  for (int kk = 0; kk < KDIM; kk += 32){
    {
      uint4 v = *(const uint4*)(A + (size_t)(row0 + ar)*KDIM + kk + aq*8);
      *(uint4*)&Asl[ar][aq*8] = v;
    }
    #pragma unroll
    for (int w2 = 0; w2 < NW; ++w2){
      int c = tid + w2*256;
      int n = c >> 2, q = c & 3;
      uint4 v = *(const uint4*)(Wt + (size_t)n*KDIM + kk + q*8);
      *(uint4*)&Wsl[n][q*8] = v;
    }
    __syncthreads();
    short8 af = *(const short8*)&Asl[wave*16 + l15][l4*8];
    #pragma unroll
    for (int t = 0; t < NT; ++t){
      short8 bf = *(const short8*)&Wsl[t*16 + l15][l4*8];
      acc[t] = __builtin_amdgcn_mfma_f32_16x16x32_bf16(af, bf, acc[t], 0, 0, 0);
    }
    __syncthreads();
  }

  #pragma unroll
  for (int t = 0; t < NT; ++t){
    int gcol = t*16 + l15;
    float b = bias ? bias[gcol] : 0.f;
    #pragma unroll
    for (int e = 0; e < 4; ++e){
      int grow = row0 + wave*16 + l4*4 + e;
      float v = acc[t][e] + b;
      if (relu) v = fmaxf(v, 0.f);
      if (rowscale) v *= rowscale[grow];
      C[(size_t)grow*NCOL + gcol] = f2bu(v);
    }
  }
}

// ---------------- unified gather: one wave per dst row ----------------
template<int F, bool OUTBF, bool SELF>
__global__ __launch_bounds__(256) void k_gather(
    const int* __restrict__ rp, const int* __restrict__ cnt,
    const int* __restrict__ csr, const float* __restrict__ scale,
    const u16* __restrict__ h, const float* __restrict__ bias,
    void* __restrict__ out, int relu)
{
  const int wave = threadIdx.x >> 6, lane = threadIdx.x & 63;
  const int d = blockIdx.x*4 + wave;
  const int k0 = rp[d], n = cnt[d];

  if constexpr (F == 128){
    const uint* h32 = (const uint*)h;
    float a0=0,a1=0,b0=0,b1=0,c0=0,c1=0,e0=0,e1=0;
    if (SELF){
      uint v = h32[(size_t)d*64 + lane];
      a0 = us2f((u16)v); a1 = us2f((u16)(v>>16));
    }
    for (int base = 0; base < n; base += 64){
      int mm = n - base; if (mm > 64) mm = 64;
      int idx = (lane < mm) ? csr[k0 + base + lane] : 0;
      int jj = 0;
      for (; jj + 4 <= mm; jj += 4){
        int s0=__shfl(idx,jj), s1=__shfl(idx,jj+1), s2=__shfl(idx,jj+2), s3=__shfl(idx,jj+3);
        uint v0 = h32[(size_t)s0*64 + lane];
        uint v1 = h32[(size_t)s1*64 + lane];
        uint v2 = h32[(size_t)s2*64 + lane];
        uint v3 = h32[(size_t)s3*64 + lane];
        a0 += us2f((u16)v0); a1 += us2f((u16)(v0>>16));
        b0 += us2f((u16)v1); b1 += us2f((u16)(v1>>16));
        c0 += us2f((u16)v2); c1 += us2f((u16)(v2>>16));
        e0 += us2f((u16)v3); e1 += us2f((u16)(v3>>16));
      }
      for (; jj < mm; ++jj){
        int s = __shfl(idx, jj);
        uint v = h32[(size_t)s*64 + lane];
        a0 += us2f((u16)v); a1 += us2f((u16)(v>>16));
      }
    }
    float sc = scale[d];
    float o0 = ((a0+b0)+(c0+e0))*sc;
    float o1 = ((a1+b1)+(c1+e1))*sc;
    if (bias){ o0 += bias[lane*2]; o1 += bias[lane*2+1]; }
    if (relu){ o0 = fmaxf(o0,0.f); o1 = fmaxf(o1,0.f); }
    if (OUTBF){
      ((uint*)out)[(size_t)d*64 + lane] = (uint)f2bu(o0) | ((uint)f2bu(o1) << 16);
    } else {
      ((float2*)out)[(size_t)d*64 + lane] = make_float2(o0, o1);
    }
  } else { // F == 64
    float a=0,b=0,c=0,e=0;
    if (SELF) a = us2f(h[(size_t)d*64 + lane]);
    for (int base = 0; base < n; base += 64){
      int mm = n - base; if (mm > 64) mm = 64;
      int idx = (lane < mm) ? csr[k0 + base + lane] : 0;
      int jj = 0;
      for (; jj + 4 <= mm; jj += 4){
        int s0=__shfl(idx,jj), s1=__shfl(idx,jj+1), s2=__shfl(idx,jj+2), s3=__shfl(idx,jj+3);
        a += us2f(h[(size_t)s0*64 + lane]);
        b += us2f(h[(size_t)s1*64 + lane]);
        c += us2f(h[(size_t)s2*64 + lane]);
        e += us2f(h[(size_t)s3*64 + lane]);
      }
      for (; jj < mm; ++jj){
        int s = __shfl(idx, jj);
        a += us2f(h[(size_t)s*64 + lane]);
      }
    }
    float o = ((a+b)+(c+e))*scale[d];
    if (bias) o += bias[lane];
    if (relu) o = fmaxf(o, 0.f);
    if (OUTBF) ((u16*)out)[(size_t)d*64 + lane] = f2bu(o);
    else       ((float*)out)[(size_t)d*64 + lane] = o;
  }
}

// ---------------- embeds + row normalize ----------------
__global__ void k_embeds(const float* __restrict__ x2, const float* __restrict__ x4,
                         void* __restrict__ out, float* __restrict__ data,
                         const int* __restrict__ flag){
  int row  = blockIdx.x*4 + (threadIdx.x >> 6);
  int lane = threadIdx.x & 63;
  if (row >= NN) return;
  size_t idx = (size_t)row*64 + lane;
  float v = 0.5f*(x2[idx] + x4[idx]);
  float ss = v*v;
  #pragma unroll
  for (int off=32; off>0; off>>=1) ss += __shfl_xor(ss, off);
  float inv = rsqrtf(ss);
  data[idx] = v*inv;
  stf(out, EMB_OFF + idx, v, flag[0]);
}

// ---------------- clustering (streaming form) ----------------
__global__ void k_mu_init(const float* __restrict__ data, float* __restrict__ mu){
  int p = blockIdx.x*256 + threadIdx.x;
  if (p >= KCL*64) return;
  int k = p >> 6, f = p & 63;
  mu[p] = data[(size_t)k*(NN/KCL)*64 + f];   // init_idx = k*(N//K)
}

// one block = 250 rows; phase1: softmax row-per-thread (tid<250);
// phase2: wave w owns cluster k=w, lane owns feature f; partials to global.
__global__ __launch_bounds__(640) void k_cluster_iter(const float* __restrict__ data,
    const float* __restrict__ mu, float* __restrict__ part, float* __restrict__ pcr,
    const int* __restrict__ nit, int iter)
{
  if (iter >= nit[0]) return;
  __shared__ float ms[640];
  __shared__ float rl[250][KCL];
  const int tid = threadIdx.x;
  ms[tid] = mu[tid];
  __syncthreads();
  const int r0 = blockIdx.x*250;
  if (tid < 250){
    const float4* dr = (const float4*)(data + (size_t)(r0 + tid)*64);
    float dot[KCL];
    #pragma unroll
    for (int k=0;k<KCL;k++) dot[k]=0.f;
    #pragma unroll
    for (int q=0;q<16;q++){
      float4 v = dr[q];
      #pragma unroll
      for (int k=0;k<KCL;k++){
        float4 m4 = *(const float4*)&ms[k*64+q*4];
        dot[k] = fmaf(v.x,m4.x,fmaf(v.y,m4.y,fmaf(v.z,m4.z,fmaf(v.w,m4.w,dot[k]))));
      }
    }
    float m = -1e30f;
    #pragma unroll
    for (int k=0;k<KCL;k++) m = fmaxf(m, 5.0f*dot[k]);
    float s = 0.f, ev[KCL];
    #pragma unroll
    for (int k=0;k<KCL;k++){ ev[k] = expf(5.0f*dot[k]-m); s += ev[k]; }
    float inv = 1.0f/s;
    #pragma unroll
    for (int k=0;k<KCL;k++) rl[tid][k] = ev[k]*inv;
  }
  __syncthreads();
  const int w = tid >> 6, f = tid & 63;
  float acc = 0.f, crp = 0.f;
  for (int t = 0; t < 250; ++t){
    float rv = rl[t][w];                         // LDS broadcast within wave
    acc = fmaf(rv, data[(size_t)(r0+t)*64 + f], acc);  // coalesced
    crp += rv;
  }
  part[(size_t)blockIdx.x*640 + tid] = acc;
  if (f == 0) pcr[blockIdx.x*16 + w] = crp;
}

__global__ void k_creduce(const float* __restrict__ part, const float* __restrict__ pcr,
                          float* __restrict__ csum, float* __restrict__ cr,
                          const int* __restrict__ nit, int iter){
  if (iter >= nit[0]) return;
  int p = threadIdx.x;                // 768 threads
  if (p < 640){
    float a = 0.f;
    for (int b = 0; b < 200; ++b) a += part[(size_t)b*640 + p];
    csum[p] = a;
  } else if (p < 640 + KCL){
    int k = p - 640;
    float a = 0.f;
    for (int b = 0; b < 200; ++b) a += pcr[b*16 + k];
    cr[k] = a;
  }
}

__global__ void k_mu_update(float* __restrict__ mu, const float* __restrict__ csum,
                            const float* __restrict__ cr,
                            const int* __restrict__ nit, int iter){
  if (iter >= nit[0]) return;
  int p = threadIdx.x;                // 640 threads
  mu[p] = csum[p] / cr[p >> 6];
}

// final assignment: row-per-thread, no dt staging (2.5KB LDS)
__global__ __launch_bounds__(256) void k_cluster_final(const float* __restrict__ data,
    const float* __restrict__ mu, void* __restrict__ out, const int* __restrict__ flag)
{
  __shared__ float ms[640];
  const int tid = threadIdx.x;
  for (int j = tid; j < 640; j += 256) ms[j] = mu[j];
  __syncthreads();
  int row = blockIdx.x*256 + tid;
  if (row >= NN) return;
  const int isbf = flag[0];
  const float4* dr = (const float4*)(data + (size_t)row*64);
  float dot[KCL];
  #pragma unroll
  for (int k=0;k<KCL;k++) dot[k]=0.f;
  #pragma unroll
  for (int q=0;q<16;q++){
    float4 v = dr[q];
    #pragma unroll
    for (int k=0;k<KCL;k++){
      float4 m4 = *(const float4*)&ms[k*64+q*4];
      dot[k] = fmaf(v.x,m4.x,fmaf(v.y,m4.y,fmaf(v.z,m4.z,fmaf(v.w,m4.w,dot[k]))));
    }
  }
  float m = -1e30f;
  #pragma unroll
  for (int k=0;k<KCL;k++) m = fmaxf(m, 5.0f*dot[k]);
  float s = 0.f, ev[KCL];
  #pragma unroll
  for (int k=0;k<KCL;k++){ ev[k] = expf(5.0f*dot[k]-m); s += ev[k]; }
  float inv = 1.0f/s;
  #pragma unroll
  for (int k=0;k<KCL;k++){
    stf(out, (size_t)D_OFF + (size_t)row*KCL + k, dot[k],    isbf);
    stf(out, (size_t)R_OFF + (size_t)row*KCL + k, ev[k]*inv, isbf);
  }
}

__global__ void k_mu_out(const float* __restrict__ mu, void* __restrict__ out,
                         const int* __restrict__ flag){
  int p = blockIdx.x*256 + threadIdx.x;
  if (p < KCL*64) stf(out, MU_OFF + p, mu[p], flag[0]);
}

// ---------------- launch ----------------
extern "C" void kernel_launch(void* const* d_in, const int* in_sizes, int n_in,
                              void* d_out, int out_size, void* d_ws, size_t ws_size,
                              hipStream_t stream)
{
  const void* x   = d_in[0];
  const int*  ei  = (const int*)d_in[1];
  const int*  hv  = (const int*)d_in[2];
  const int*  he  = (const int*)d_in[3];
  const void* gW1 = d_in[4];
  const void* gb1 = d_in[5];
  const void* gW2 = d_in[6];
  const void* gb2 = d_in[7];
  const void* hW1 = d_in[8];
  const void* hb1 = d_in[9];
  const void* hW2 = d_in[10];
  const void* hb2 = d_in[11];
  const int*  nit = (const int*)d_in[12];

  float* ws = (float*)d_ws;
  size_t o = 0;
  u16*   xb  = (u16*)(ws + o); o += (size_t)NP*128;   // x bf16 NP x 256
  u16*   BAb = (u16*)(ws + o); o += (size_t)NP*64;    // GEMM out bf16 NP x 128
  u16*   BBb = (u16*)(ws + o); o += (size_t)NP*64;    // x1 bf16; later dataf f32
  u16*   BCb = (u16*)(ws + o); o += (size_t)NP*64;    // x3 bf16
  u16*   BDb = (u16*)(ws + o); o += (size_t)NEH*64;   // e_feat bf16 NEH x 128
  u16*  gW1t = (u16*)(ws + o); o += 16384;
  u16*  hW1t = (u16*)(ws + o); o += 16384;
  u16*  gW2t = (u16*)(ws + o); o += 4096;
  u16*  hW2t = (u16*)(ws + o); o += 4096;
  float* gb1f = ws + o; o += 128;
  float* hb1f = ws + o; o += 128;
  float* gb2f = ws + o; o += 64;
  float* hb2f = ws + o; o += 64;
  float* dinv = ws + o; o += 50048;
  float* invv = ws + o; o += 50048;
  float* inve = ws + o; o += 10048;
  float* mu   = ws + o; o += 640;
  float* csum = ws + o; o += 640;
  float* cr   = ws + o; o += 64;
  float* part = ws + o; o += 200*640;   // cluster partials
  float* pcr  = ws + o; o += 200*16;
  int*   dflg = (int*)(ws + o); o += 16;
  float* x2f   = (float*)xb;                 // aliases (xb dead by then)
  float* x4f   = (float*)xb + (size_t)NP*64;
  float* dataf = (float*)BBb;                // alias (BBb dead by then)
  // int region (CSR)
  int* ib = (int*)(ws + o);
  size_t io = 0;
  int* cg    = ib + io; io += NN;
  int* cv    = ib + io; io += NN;
  int* ce    = ib + io; io += NEH + 48;
  int* rp_g  = ib + io; io += NN;
  int* rp_v  = ib + io; io += NN;
  int* rp_e  = ib + io; io += NEH + 48;
  int* csr_g = ib + io; io += EE;
  int* csr_e = ib + io; io += NINC;
  int* csr_v = ib + io; io += NINC;
  int* HAg   = ib + io; io += 128*250;
  int* HAv   = ib + io; io += 64*250;
  int* HAe   = ib + io; io += 64*250;
  int* bsg   = ib + io; io += 256;
  int* bsv   = ib + io; io += 256;
  int* bse   = ib + io; io += 256;
  u32* pg = (u32*)(ib + io); io += EE;      // packed buckets
  u32* pv = (u32*)(ib + io); io += NINC;
  u32* pe = (u32*)(ib + io); io += NINC;

  const int* srcp = ei;
  const int* dstp = ei + EE;
  dim3 B(256);
  const int NBP = (NP + 255)/256;

  // dtype detection + input prep
  k_detect<<<dim3(1), B, 0, stream>>>((const u16*)x, dflg);
  k_aconv<<<dim3(12500), B, 0, stream>>>(x, xb, dflg);
  k_wprep<<<dim3(128), B, 0, stream>>>(gW1, hW1, gW2, hW2, gb1, hb1, gb2, hb2,
                                       gW1t, hW1t, gW2t, hW2t,
                                       gb1f, hb1f, gb2f, hb2f, dflg);

  // ---- two-pass bucket CSR build (250 buckets) ----
  k_histA<250,200><<<dim3(128), B, 0, stream>>>(dstp, HAg, 6250);
  k_histA<250,200><<<dim3(64),  B, 0, stream>>>(hv,   HAv, 3125);
  k_histA<250, 40><<<dim3(64),  B, 0, stream>>>(he,   HAe, 3125);
  k_scanA_all<<<dim3(3), B, 0, stream>>>(HAg, HAv, HAe, bsg, bsv, bse);
  k_fillA<250,200><<<dim3(128), B, 0, stream>>>(dstp, srcp, HAg, bsg, pg, 6250);
  k_fillA<250,200><<<dim3(64),  B, 0, stream>>>(hv,   he,   HAv, bsv, pv, 3125);
  k_fillA<250, 40><<<dim3(64),  B, 0, stream>>>(he,   hv,   HAe, bse, pe, 3125);
  k_fillB<200><<<dim3(250), B, 0, stream>>>(pg, bsg, csr_g, cg, rp_g);
  k_fillB<200><<<dim3(250), B, 0, stream>>>(pv, bsv, csr_v, cv, rp_v);
  k_fillB< 40><<<dim3(250), B, 0, stream>>>(pe, bse, csr_e, ce, rp_e);
  k_invs<<<dim3(NBP), B, 0, stream>>>(cg, cv, ce, dinv, invv, inve);

  const int NB = NP/64;                 // 782 MFMA blocks
  // ---- GCN layer 1: BAb = (x@gW1)*dinv[row] ; x1 = gather+gb1, relu ----
  k_gemm_mfma<256,128><<<dim3(NB), B, 0, stream>>>(xb, gW1t, nullptr, dinv, BAb, 0);
  k_gather<128,true,true><<<dim3(NN/4), B, 0, stream>>>(rp_g, cg, csr_g, dinv,
                                                        BAb, gb1f, BBb, 1);
  // ---- HGNNP layer 1 ----
  k_gemm_mfma<256,128><<<dim3(NB), B, 0, stream>>>(xb, hW1t, hb1f, nullptr, BAb, 0);
  k_gather<128,true,false><<<dim3(NEH/4), B, 0, stream>>>(rp_e, ce, csr_e, inve,
                                                          BAb, nullptr, BDb, 0);
  k_gather<128,true,false><<<dim3(NN/4), B, 0, stream>>>(rp_v, cv, csr_v, invv,
                                                         BDb, nullptr, BCb, 1);
  // ---- GCN layer 2 ----
  k_gemm_mfma<128,64><<<dim3(NB), B, 0, stream>>>(BBb, gW2t, nullptr, dinv, BAb, 0);
  k_gather<64,false,true><<<dim3(NN/4), B, 0, stream>>>(rp_g, cg, csr_g, dinv,
                                                        BAb, gb2f, x2f, 0);
  // ---- HGNNP layer 2 ----
  k_gemm_mfma<128,64><<<dim3(NB), B, 0, stream>>>(BCb, hW2t, hb2f, nullptr, BAb, 0);
  k_gather<64,true,false><<<dim3(NEH/4), B, 0, stream>>>(rp_e, ce, csr_e, inve,
                                                         BAb, nullptr, BDb, 0);
  k_gather<64,false,false><<<dim3(NN/4), B, 0, stream>>>(rp_v, cv, csr_v, invv,
                                                         BDb, nullptr, x4f, 0);

  // ---- embeds + normalized rows -> dataf ----
  k_embeds<<<dim3((NN+3)/4), B, 0, stream>>>(x2f, x4f, d_out, dataf, dflg);

  // ---- clustering (streaming) ----
  k_mu_init<<<dim3(3), B, 0, stream>>>(dataf, mu);
  for (int it = 0; it < 4; ++it){   // gated by iter < *num_iter (setup: 1)
    k_cluster_iter<<<dim3(200), dim3(640), 0, stream>>>(dataf, mu, part, pcr, nit, it);
    k_creduce     <<<dim3(1),   dim3(768), 0, stream>>>(part, pcr, csum, cr, nit, it);
    k_mu_update   <<<dim3(1),   dim3(640), 0, stream>>>(mu, csum, cr, nit, it);
  }
  k_cluster_final<<<dim3(196), B, 0, stream>>>(dataf, mu, d_out, dflg);
  k_mu_out       <<<dim3(3),  B, 0, stream>>>(mu, d_out, dflg);
}

// Round 15
// 372.268 us; speedup vs baseline: 1.0221x; 1.0221x over previous
//
#include <hip/hip_runtime.h>
#include <hip/hip_bf16.h>

// HGNNP_GCN + ClusterNet forward, MI355X (round 15).
// R14 counters: k_cluster_final 52us, VGPR 256, occupancy 0.03% -> row-per-
// thread over row-major data = 256B-strided lane access (1/64 per-instr
// efficiency) + register blowup. This round: both cluster kernels use 64-row
// tiles with cooperative coalesced LDS staging, thread=(k,row) dot phase,
// wave-0 softmax, thread=(k,f) outer-product partials, two-level reduce.

#define NN   50000   // nodes (= 250*200)
#define NP   50048   // padded rows (782 * 64)
#define EE   800000  // directed edges (= 128*6250)
#define NINC 200000  // incidence entries (= 64*3125)
#define NEH  10000   // hyperedges (= 250*40)
#define KCL  10      // clusters
#define CBLK 782     // cluster blocks (ceil(NN/64))

// output element offsets (flat concat: mu | r | embeds | dist)
#define MU_OFF  0
#define R_OFF   640
#define EMB_OFF 500640
#define D_OFF   3700640

typedef __hip_bfloat16 bf16;
typedef unsigned short u16;
typedef unsigned int   u32;
typedef __attribute__((ext_vector_type(8))) short short8;
typedef __attribute__((ext_vector_type(4))) float f32x4;

__device__ __forceinline__ float b2f(bf16 v){ return __bfloat162float(v); }
__device__ __forceinline__ float us2f(u16 u){ return __uint_as_float(((unsigned)u) << 16); }
__device__ __forceinline__ u16 f2bu(float f){
  unsigned u = __float_as_uint(f);
  return (u16)((u + 0x7fffu + ((u >> 16) & 1u)) >> 16);   // RNE
}
__device__ __forceinline__ bf16 f2b(float f){
  u16 r = f2bu(f);
  bf16 h;
  reinterpret_cast<u16&>(h) = r;
  return h;
}
__device__ __forceinline__ float ldf(const void* p, size_t i, int isbf){
  return isbf ? b2f(((const bf16*)p)[i]) : ((const float*)p)[i];
}
__device__ __forceinline__ void stf(void* p, size_t i, float v, int isbf){
  if (isbf) ((bf16*)p)[i] = f2b(v);
  else      ((float*)p)[i] = v;
}

// ---------------- dtype detector ----------------
__global__ void k_detect(const u16* __restrict__ xr, int* flag){
  __shared__ int bad;
  if (threadIdx.x == 0) bad = 0;
  __syncthreads();
  for (int i = threadIdx.x; i < 4096; i += 256){
    int e = (xr[i] >> 7) & 0xFF;
    if (e >= 0xEF) bad = 1;     // f32 low-halves have random exponents
  }
  __syncthreads();
  if (threadIdx.x == 0) *flag = bad ? 0 : 1;   // 1 = bf16, 0 = f32
}

// ---------------- input prep ----------------
__global__ void k_aconv(const void* __restrict__ x, u16* __restrict__ xb,
                        const int* __restrict__ flag){
  int i = blockIdx.x*256 + threadIdx.x;      // one ushort4 (4 elems)
  const int n4 = NN*256/4;
  if (i >= n4) return;
  ushort4 o;
  if (flag[0]){
    o = ((const ushort4*)x)[i];
  } else {
    float4 v = ((const float4*)x)[i];
    o = make_ushort4(f2bu(v.x), f2bu(v.y), f2bu(v.z), f2bu(v.w));
  }
  ((ushort4*)xb)[i] = o;
}

__global__ void k_wprep(const void* gW1, const void* hW1, const void* gW2, const void* hW2,
                        const void* gb1, const void* hb1, const void* gb2, const void* hb2,
                        u16* gW1t, u16* hW1t, u16* gW2t, u16* hW2t,
                        float* gb1f, float* hb1f, float* gb2f, float* hb2f,
                        const int* __restrict__ flag){
  const int isbf = flag[0];
  int i = blockIdx.x*256 + threadIdx.x;
  if (i < 256*128){                    // Wt[n][k] = W[k][n], 128x256
    int n = i >> 8, k = i & 255;
    gW1t[i] = f2bu(ldf(gW1, (size_t)k*128 + n, isbf));
    hW1t[i] = f2bu(ldf(hW1, (size_t)k*128 + n, isbf));
  }
  if (i < 64*128){                     // 64x128
    int n = i >> 7, k = i & 127;
    gW2t[i] = f2bu(ldf(gW2, (size_t)k*64 + n, isbf));
    hW2t[i] = f2bu(ldf(hW2, (size_t)k*64 + n, isbf));
  }
  if (i < 128){ gb1f[i] = ldf(gb1,i,isbf); hb1f[i] = ldf(hb1,i,isbf); }
  if (i < 64) { gb2f[i] = ldf(gb2,i,isbf); hb2f[i] = ldf(hb2,i,isbf); }
}

// ---------------- two-pass bucket CSR build ----------------
template<int NBKT, int NPB>
__global__ __launch_bounds__(256) void k_histA(const int* __restrict__ key,
                                               int* __restrict__ HA, int chunk){
  __shared__ u32 hist[NBKT];
  for (int i = threadIdx.x; i < NBKT; i += 256) hist[i] = 0;
  __syncthreads();
  int base = blockIdx.x*chunk;
  for (int i = threadIdx.x; i < chunk; i += 256)
    atomicAdd(&hist[key[base+i]/NPB], 1u);
  __syncthreads();
  int* out = HA + blockIdx.x*NBKT;
  for (int i = threadIdx.x; i < NBKT; i += 256) out[i] = (int)hist[i];
}

// per-bucket prefix over chunks (in place) + bucket starts bs[0..250]
__global__ void k_scanA_all(int* HAg, int* HAv, int* HAe,
                            int* bsg, int* bsv, int* bse){
  int* HA; int* bs; int nch;
  if (blockIdx.x == 0){ HA = HAg; bs = bsg; nch = 128; }
  else if (blockIdx.x == 1){ HA = HAv; bs = bsv; nch = 64; }
  else { HA = HAe; bs = bse; nch = 64; }
  __shared__ int s[256];
  int t = threadIdx.x;
  int run = 0;
  if (t < 250){
    for (int c = 0; c < nch; ++c){
      int v = HA[c*250 + t];
      HA[c*250 + t] = run;       // prefix-before-chunk
      run += v;
    }
  }
  int own = (t < 250) ? run : 0;
  s[t] = own; __syncthreads();
  #pragma unroll
  for (int off = 1; off < 256; off <<= 1){
    int add = (t >= off) ? s[t-off] : 0;
    __syncthreads();
    s[t] += add;
    __syncthreads();
  }
  if (t < 250) bs[t] = s[t] - own;   // exclusive bucket start
  if (t == 255) bs[250] = s[255];    // total
}

// Pass A fill: partition into buckets as packed u32 (lk<<16 | val).
template<int NBKT, int NPB>
__global__ __launch_bounds__(256) void k_fillA(const int* __restrict__ key,
    const int* __restrict__ val, const int* __restrict__ HA,
    const int* __restrict__ bs, u32* __restrict__ packed, int chunk){
  __shared__ u32 cur[NBKT];
  const int* pre = HA + blockIdx.x*NBKT;
  for (int i = threadIdx.x; i < NBKT; i += 256) cur[i] = (u32)(bs[i] + pre[i]);
  __syncthreads();
  int base = blockIdx.x*chunk;
  for (int i = threadIdx.x; i < chunk; i += 256){
    int k = key[base+i];
    int b = k / NPB;
    u32 pos = atomicAdd(&cur[b], 1u);
    packed[pos] = ((u32)(k - b*NPB) << 16) | (u32)val[base+i];
  }
}

// Pass B: one block per bucket; csr scatter in a private window.
template<int NPB>
__global__ __launch_bounds__(256) void k_fillB(const u32* __restrict__ packed,
    const int* __restrict__ bs, int* __restrict__ csr,
    int* __restrict__ cnt, int* __restrict__ rp){
  __shared__ u32 hist[NPB];
  __shared__ int s[256];
  __shared__ u32 cur[NPB];
  const int b = blockIdx.x;
  const int s0 = bs[b], m = bs[b+1] - s0;
  const int t = threadIdx.x;
  for (int i = t; i < NPB; i += 256) hist[i] = 0;
  __syncthreads();
  for (int i = t; i < m; i += 256)
    atomicAdd(&hist[packed[s0+i] >> 16], 1u);
  __syncthreads();
  int own = (t < NPB) ? (int)hist[t] : 0;
  s[t] = own; __syncthreads();
  #pragma unroll
  for (int off = 1; off < 256; off <<= 1){
    int add = (t >= off) ? s[t-off] : 0;
    __syncthreads();
    s[t] += add;
    __syncthreads();
  }
  if (t < NPB){
    int excl = s[t] - own;
    cnt[b*NPB + t] = own;
    rp[b*NPB + t]  = s0 + excl;
    cur[t] = (u32)(s0 + excl);
  }
  __syncthreads();
  for (int i = t; i < m; i += 256){
    u32 p = packed[s0+i];
    u32 pos = atomicAdd(&cur[p >> 16], 1u);
    csr[pos] = (int)(p & 0xffffu);
  }
}

__global__ void k_invs(const int* __restrict__ cg, const int* __restrict__ cv,
                       const int* __restrict__ ce,
                       float* dinv, float* invv, float* inve){
  int i = blockIdx.x*256 + threadIdx.x;
  if (i < NN){
    float d = 1.0f + (float)cg[i];     // self-loop included
    dinv[i] = rsqrtf(d);
    invv[i] = 1.0f / fmaxf((float)cv[i], 1.0f);
  } else if (i < NP){
    dinv[i] = 0.f;                     // pad rows
  }
  if (i < NEH) inve[i] = 1.0f / fmaxf((float)ce[i], 1.0f);
}

// ---------------- MFMA GEMM ----------------
template<int KDIM, int NCOL>
__global__ __launch_bounds__(256) void k_gemm_mfma(
    const u16* __restrict__ A, const u16* __restrict__ Wt,
    const float* __restrict__ bias, const float* __restrict__ rowscale,
    u16* __restrict__ C, int relu)
{
  constexpr int NT  = NCOL/16;
  constexpr int LDA = 40;
  __shared__ __align__(16) u16 Asl[64][LDA];
  __shared__ __align__(16) u16 Wsl[NCOL][LDA];
  const int tid  = threadIdx.x;
  const int wave = tid >> 6, lane = tid & 63;
  const int l15 = lane & 15, l4 = lane >> 4;
  const int row0 = blockIdx.x * 64;
  const int ar = tid >> 2, aq = tid & 3;
  constexpr int NW = NCOL*4/256;

  f32x4 acc[NT] = {};

  for (int kk = 0; kk < KDIM; kk += 32){
    {
      uint4 v = *(const uint4*)(A + (size_t)(row0 + ar)*KDIM + kk + aq*8);
      *(uint4*)&Asl[ar][aq*8] = v;
    }
    #pragma unroll
    for (int w2 = 0; w2 < NW; ++w2){
      int c = tid + w2*256;
      int n = c >> 2, q = c & 3;
      uint4 v = *(const uint4*)(Wt + (size_t)n*KDIM + kk + q*8);
      *(uint4*)&Wsl[n][q*8] = v;
    }
    __syncthreads();
    short8 af = *(const short8*)&Asl[wave*16 + l15][l4*8];
    #pragma unroll
    for (int t = 0; t < NT; ++t){
      short8 bf = *(const short8*)&Wsl[t*16 + l15][l4*8];
      acc[t] = __builtin_amdgcn_mfma_f32_16x16x32_bf16(af, bf, acc[t], 0, 0, 0);
    }
    __syncthreads();
  }

  #pragma unroll
  for (int t = 0; t < NT; ++t){
    int gcol = t*16 + l15;
    float b = bias ? bias[gcol] : 0.f;
    #pragma unroll
    for (int e = 0; e < 4; ++e){
      int grow = row0 + wave*16 + l4*4 + e;
      float v = acc[t][e] + b;
      if (relu) v = fmaxf(v, 0.f);
      if (rowscale) v *= rowscale[grow];
      C[(size_t)grow*NCOL + gcol] = f2bu(v);
    }
  }
}

// ---------------- unified gather: one wave per dst row ----------------
template<int F, bool OUTBF, bool SELF>
__global__ __launch_bounds__(256) void k_gather(
    const int* __restrict__ rp, const int* __restrict__ cnt,
    const int* __restrict__ csr, const float* __restrict__ scale,
    const u16* __restrict__ h, const float* __restrict__ bias,
    void* __restrict__ out, int relu)
{
  const int wave = threadIdx.x >> 6, lane = threadIdx.x & 63;
  const int d = blockIdx.x*4 + wave;
  const int k0 = rp[d], n = cnt[d];

  if constexpr (F == 128){
    const uint* h32 = (const uint*)h;
    float a0=0,a1=0,b0=0,b1=0,c0=0,c1=0,e0=0,e1=0;
    if (SELF){
      uint v = h32[(size_t)d*64 + lane];
      a0 = us2f((u16)v); a1 = us2f((u16)(v>>16));
    }
    for (int base = 0; base < n; base += 64){
      int mm = n - base; if (mm > 64) mm = 64;
      int idx = (lane < mm) ? csr[k0 + base + lane] : 0;
      int jj = 0;
      for (; jj + 4 <= mm; jj += 4){
        int s0=__shfl(idx,jj), s1=__shfl(idx,jj+1), s2=__shfl(idx,jj+2), s3=__shfl(idx,jj+3);
        uint v0 = h32[(size_t)s0*64 + lane];
        uint v1 = h32[(size_t)s1*64 + lane];
        uint v2 = h32[(size_t)s2*64 + lane];
        uint v3 = h32[(size_t)s3*64 + lane];
        a0 += us2f((u16)v0); a1 += us2f((u16)(v0>>16));
        b0 += us2f((u16)v1); b1 += us2f((u16)(v1>>16));
        c0 += us2f((u16)v2); c1 += us2f((u16)(v2>>16));
        e0 += us2f((u16)v3); e1 += us2f((u16)(v3>>16));
      }
      for (; jj < mm; ++jj){
        int s = __shfl(idx, jj);
        uint v = h32[(size_t)s*64 + lane];
        a0 += us2f((u16)v); a1 += us2f((u16)(v>>16));
      }
    }
    float sc = scale[d];
    float o0 = ((a0+b0)+(c0+e0))*sc;
    float o1 = ((a1+b1)+(c1+e1))*sc;
    if (bias){ o0 += bias[lane*2]; o1 += bias[lane*2+1]; }
    if (relu){ o0 = fmaxf(o0,0.f); o1 = fmaxf(o1,0.f); }
    if (OUTBF){
      ((uint*)out)[(size_t)d*64 + lane] = (uint)f2bu(o0) | ((uint)f2bu(o1) << 16);
    } else {
      ((float2*)out)[(size_t)d*64 + lane] = make_float2(o0, o1);
    }
  } else { // F == 64
    float a=0,b=0,c=0,e=0;
    if (SELF) a = us2f(h[(size_t)d*64 + lane]);
    for (int base = 0; base < n; base += 64){
      int mm = n - base; if (mm > 64) mm = 64;
      int idx = (lane < mm) ? csr[k0 + base + lane] : 0;
      int jj = 0;
      for (; jj + 4 <= mm; jj += 4){
        int s0=__shfl(idx,jj), s1=__shfl(idx,jj+1), s2=__shfl(idx,jj+2), s3=__shfl(idx,jj+3);
        a += us2f(h[(size_t)s0*64 + lane]);
        b += us2f(h[(size_t)s1*64 + lane]);
        c += us2f(h[(size_t)s2*64 + lane]);
        e += us2f(h[(size_t)s3*64 + lane]);
      }
      for (; jj < mm; ++jj){
        int s = __shfl(idx, jj);
        a += us2f(h[(size_t)s*64 + lane]);
      }
    }
    float o = ((a+b)+(c+e))*scale[d];
    if (bias) o += bias[lane];
    if (relu) o = fmaxf(o, 0.f);
    if (OUTBF) ((u16*)out)[(size_t)d*64 + lane] = f2bu(o);
    else       ((float*)out)[(size_t)d*64 + lane] = o;
  }
}

// ---------------- embeds + row normalize ----------------
__global__ void k_embeds(const float* __restrict__ x2, const float* __restrict__ x4,
                         void* __restrict__ out, float* __restrict__ data,
                         const int* __restrict__ flag){
  int row  = blockIdx.x*4 + (threadIdx.x >> 6);
  int lane = threadIdx.x & 63;
  if (row >= NN) return;
  size_t idx = (size_t)row*64 + lane;
  float v = 0.5f*(x2[idx] + x4[idx]);
  float ss = v*v;
  #pragma unroll
  for (int off=32; off>0; off>>=1) ss += __shfl_xor(ss, off);
  float inv = rsqrtf(ss);
  data[idx] = v*inv;
  stf(out, EMB_OFF + idx, v, flag[0]);
}

// ---------------- clustering (coalesced tile form) ----------------
__global__ void k_mu_init(const float* __restrict__ data, float* __restrict__ mu){
  int p = blockIdx.x*256 + threadIdx.x;
  if (p >= KCL*64) return;
  int k = p >> 6, f = p & 63;
  mu[p] = data[(size_t)k*(NN/KCL)*64 + f];   // init_idx = k*(N//K)
}

// 64 rows/block, 640 threads. Stage dt coalesced; dot by (k,row);
// softmax by wave0; outer-product partials by (k,f).
__global__ __launch_bounds__(640) void k_cluster_iter(const float* __restrict__ data,
    const float* __restrict__ mu, float* __restrict__ part, float* __restrict__ pcr,
    const int* __restrict__ nit, int iter)
{
  if (iter >= nit[0]) return;
  __shared__ float ms[640];
  __shared__ float dt[64][65];
  __shared__ float ds[64][11];
  const int tid = threadIdx.x;
  ms[tid] = mu[tid];
  const int base = blockIdx.x*64;
  for (int i = tid; i < 4096; i += 640){
    int r = i >> 6, f = i & 63;
    int grow = base + r;
    dt[r][f] = (grow < NN) ? data[(size_t)grow*64 + f] : 0.f;
  }
  __syncthreads();
  {
    const int row = tid & 63, k = tid >> 6;
    float dot = 0.f;
    #pragma unroll 16
    for (int f = 0; f < 64; ++f)
      dot = fmaf(dt[row][f], ms[k*64 + f], dot);
    ds[row][k] = dot;
  }
  __syncthreads();
  if (tid < 64){
    float dot[KCL];
    #pragma unroll
    for (int k = 0; k < KCL; ++k) dot[k] = ds[tid][k];
    float m = -1e30f;
    #pragma unroll
    for (int k = 0; k < KCL; ++k) m = fmaxf(m, 5.0f*dot[k]);
    float s = 0.f, ev[KCL];
    #pragma unroll
    for (int k = 0; k < KCL; ++k){ ev[k] = expf(5.0f*dot[k]-m); s += ev[k]; }
    float inv = (base + tid < NN) ? 1.0f/s : 0.f;   // pad rows contribute 0
    #pragma unroll
    for (int k = 0; k < KCL; ++k) ds[tid][k] = ev[k]*inv;
  }
  __syncthreads();
  {
    const int f = tid & 63, k = tid >> 6;
    float acc = 0.f, crp = 0.f;
    #pragma unroll 8
    for (int t = 0; t < 64; ++t){
      float rv = ds[t][k];               // broadcast within wave
      acc = fmaf(rv, dt[t][f], acc);
      crp += rv;
    }
    part[(size_t)blockIdx.x*640 + tid] = acc;
    if (f == 0) pcr[blockIdx.x*16 + k] = crp;
  }
}

// level-1 reduce: 40 blocks, 20 tiles each
__global__ void k_cred1(const float* __restrict__ part, const float* __restrict__ pcr,
                        float* __restrict__ p2, float* __restrict__ pc2,
                        const int* __restrict__ nit, int iter){
  if (iter >= nit[0]) return;
  int b = blockIdx.x, t = threadIdx.x;
  int r0 = b*20, r1 = r0 + 20; if (r1 > CBLK) r1 = CBLK;
  if (t < 640){
    float a = 0.f;
    for (int r = r0; r < r1; ++r) a += part[(size_t)r*640 + t];
    p2[(size_t)b*640 + t] = a;
  } else if (t < 640 + KCL){
    int k = t - 640;
    float a = 0.f;
    for (int r = r0; r < r1; ++r) a += pcr[r*16 + k];
    pc2[b*16 + k] = a;
  }
}

// level-2 reduce: 1 block
__global__ void k_cred2(const float* __restrict__ p2, const float* __restrict__ pc2,
                        float* __restrict__ csum, float* __restrict__ cr,
                        const int* __restrict__ nit, int iter){
  if (iter >= nit[0]) return;
  int t = threadIdx.x;
  if (t < 640){
    float a = 0.f;
    #pragma unroll
    for (int b = 0; b < 40; ++b) a += p2[(size_t)b*640 + t];
    csum[t] = a;
  } else if (t < 640 + KCL){
    int k = t - 640;
    float a = 0.f;
    #pragma unroll
    for (int b = 0; b < 40; ++b) a += pc2[b*16 + k];
    cr[k] = a;
  }
}

__global__ void k_mu_update(float* __restrict__ mu, const float* __restrict__ csum,
                            const float* __restrict__ cr,
                            const int* __restrict__ nit, int iter){
  if (iter >= nit[0]) return;
  int p = threadIdx.x;                // 640 threads
  mu[p] = csum[p] / cr[p >> 6];
}

// final: same tile structure; wave0 writes r/dist
__global__ __launch_bounds__(640) void k_cluster_final(const float* __restrict__ data,
    const float* __restrict__ mu, void* __restrict__ out, const int* __restrict__ flag)
{
  __shared__ float ms[640];
  __shared__ float dt[64][65];
  __shared__ float ds[64][11];
  const int tid = threadIdx.x;
  ms[tid] = mu[tid];
  const int base = blockIdx.x*64;
  for (int i = tid; i < 4096; i += 640){
    int r = i >> 6, f = i & 63;
    int grow = base + r;
    dt[r][f] = (grow < NN) ? data[(size_t)grow*64 + f] : 0.f;
  }
  __syncthreads();
  {
    const int row = tid & 63, k = tid >> 6;
    float dot = 0.f;
    #pragma unroll 16
    for (int f = 0; f < 64; ++f)
      dot = fmaf(dt[row][f], ms[k*64 + f], dot);
    ds[row][k] = dot;
  }
  __syncthreads();
  if (tid < 64 && base + tid < NN){
    const int row = base + tid;
    const int isbf = flag[0];
    float dot[KCL];
    #pragma unroll
    for (int k = 0; k < KCL; ++k) dot[k] = ds[tid][k];
    float m = -1e30f;
    #pragma unroll
    for (int k = 0; k < KCL; ++k) m = fmaxf(m, 5.0f*dot[k]);
    float s = 0.f, ev[KCL];
    #pragma unroll
    for (int k = 0; k < KCL; ++k){ ev[k] = expf(5.0f*dot[k]-m); s += ev[k]; }
    float inv = 1.0f/s;
    #pragma unroll
    for (int k = 0; k < KCL; ++k){
      stf(out, (size_t)D_OFF + (size_t)row*KCL + k, dot[k],    isbf);
      stf(out, (size_t)R_OFF + (size_t)row*KCL + k, ev[k]*inv, isbf);
    }
  }
}

__global__ void k_mu_out(const float* __restrict__ mu, void* __restrict__ out,
                         const int* __restrict__ flag){
  int p = blockIdx.x*256 + threadIdx.x;
  if (p < KCL*64) stf(out, MU_OFF + p, mu[p], flag[0]);
}

// ---------------- launch ----------------
extern "C" void kernel_launch(void* const* d_in, const int* in_sizes, int n_in,
                              void* d_out, int out_size, void* d_ws, size_t ws_size,
                              hipStream_t stream)
{
  const void* x   = d_in[0];
  const int*  ei  = (const int*)d_in[1];
  const int*  hv  = (const int*)d_in[2];
  const int*  he  = (const int*)d_in[3];
  const void* gW1 = d_in[4];
  const void* gb1 = d_in[5];
  const void* gW2 = d_in[6];
  const void* gb2 = d_in[7];
  const void* hW1 = d_in[8];
  const void* hb1 = d_in[9];
  const void* hW2 = d_in[10];
  const void* hb2 = d_in[11];
  const int*  nit = (const int*)d_in[12];

  float* ws = (float*)d_ws;
  size_t o = 0;
  u16*   xb  = (u16*)(ws + o); o += (size_t)NP*128;   // x bf16 NP x 256
  u16*   BAb = (u16*)(ws + o); o += (size_t)NP*64;    // GEMM out bf16 NP x 128
  u16*   BBb = (u16*)(ws + o); o += (size_t)NP*64;    // x1 bf16; later dataf f32
  u16*   BCb = (u16*)(ws + o); o += (size_t)NP*64;    // x3 bf16
  u16*   BDb = (u16*)(ws + o); o += (size_t)NEH*64;   // e_feat bf16 NEH x 128
  u16*  gW1t = (u16*)(ws + o); o += 16384;
  u16*  hW1t = (u16*)(ws + o); o += 16384;
  u16*  gW2t = (u16*)(ws + o); o += 4096;
  u16*  hW2t = (u16*)(ws + o); o += 4096;
  float* gb1f = ws + o; o += 128;
  float* hb1f = ws + o; o += 128;
  float* gb2f = ws + o; o += 64;
  float* hb2f = ws + o; o += 64;
  float* dinv = ws + o; o += 50048;
  float* invv = ws + o; o += 50048;
  float* inve = ws + o; o += 10048;
  float* mu   = ws + o; o += 640;
  float* csum = ws + o; o += 640;
  float* cr   = ws + o; o += 64;
  float* part = ws + o; o += (size_t)CBLK*640;   // cluster partials
  float* pcr  = ws + o; o += CBLK*16;
  float* p2   = ws + o; o += 40*640;
  float* pc2  = ws + o; o += 40*16;
  int*   dflg = (int*)(ws + o); o += 16;
  float* x2f   = (float*)xb;                 // aliases (xb dead by then)
  float* x4f   = (float*)xb + (size_t)NP*64;
  float* dataf = (float*)BBb;                // alias (BBb dead by then)
  // int region (CSR)
  int* ib = (int*)(ws + o);
  size_t io = 0;
  int* cg    = ib + io; io += NN;
  int* cv    = ib + io; io += NN;
  int* ce    = ib + io; io += NEH + 48;
  int* rp_g  = ib + io; io += NN;
  int* rp_v  = ib + io; io += NN;
  int* rp_e  = ib + io; io += NEH + 48;
  int* csr_g = ib + io; io += EE;
  int* csr_e = ib + io; io += NINC;
  int* csr_v = ib + io; io += NINC;
  int* HAg   = ib + io; io += 128*250;
  int* HAv   = ib + io; io += 64*250;
  int* HAe   = ib + io; io += 64*250;
  int* bsg   = ib + io; io += 256;
  int* bsv   = ib + io; io += 256;
  int* bse   = ib + io; io += 256;
  u32* pg = (u32*)(ib + io); io += EE;      // packed buckets
  u32* pv = (u32*)(ib + io); io += NINC;
  u32* pe = (u32*)(ib + io); io += NINC;

  const int* srcp = ei;
  const int* dstp = ei + EE;
  dim3 B(256);
  const int NBP = (NP + 255)/256;

  // dtype detection + input prep
  k_detect<<<dim3(1), B, 0, stream>>>((const u16*)x, dflg);
  k_aconv<<<dim3(12500), B, 0, stream>>>(x, xb, dflg);
  k_wprep<<<dim3(128), B, 0, stream>>>(gW1, hW1, gW2, hW2, gb1, hb1, gb2, hb2,
                                       gW1t, hW1t, gW2t, hW2t,
                                       gb1f, hb1f, gb2f, hb2f, dflg);

  // ---- two-pass bucket CSR build (250 buckets) ----
  k_histA<250,200><<<dim3(128), B, 0, stream>>>(dstp, HAg, 6250);
  k_histA<250,200><<<dim3(64),  B, 0, stream>>>(hv,   HAv, 3125);
  k_histA<250, 40><<<dim3(64),  B, 0, stream>>>(he,   HAe, 3125);
  k_scanA_all<<<dim3(3), B, 0, stream>>>(HAg, HAv, HAe, bsg, bsv, bse);
  k_fillA<250,200><<<dim3(128), B, 0, stream>>>(dstp, srcp, HAg, bsg, pg, 6250);
  k_fillA<250,200><<<dim3(64),  B, 0, stream>>>(hv,   he,   HAv, bsv, pv, 3125);
  k_fillA<250, 40><<<dim3(64),  B, 0, stream>>>(he,   hv,   HAe, bse, pe, 3125);
  k_fillB<200><<<dim3(250), B, 0, stream>>>(pg, bsg, csr_g, cg, rp_g);
  k_fillB<200><<<dim3(250), B, 0, stream>>>(pv, bsv, csr_v, cv, rp_v);
  k_fillB< 40><<<dim3(250), B, 0, stream>>>(pe, bse, csr_e, ce, rp_e);
  k_invs<<<dim3(NBP), B, 0, stream>>>(cg, cv, ce, dinv, invv, inve);

  const int NB = NP/64;                 // 782 MFMA blocks
  // ---- GCN layer 1: BAb = (x@gW1)*dinv[row] ; x1 = gather+gb1, relu ----
  k_gemm_mfma<256,128><<<dim3(NB), B, 0, stream>>>(xb, gW1t, nullptr, dinv, BAb, 0);
  k_gather<128,true,true><<<dim3(NN/4), B, 0, stream>>>(rp_g, cg, csr_g, dinv,
                                                        BAb, gb1f, BBb, 1);
  // ---- HGNNP layer 1 ----
  k_gemm_mfma<256,128><<<dim3(NB), B, 0, stream>>>(xb, hW1t, hb1f, nullptr, BAb, 0);
  k_gather<128,true,false><<<dim3(NEH/4), B, 0, stream>>>(rp_e, ce, csr_e, inve,
                                                          BAb, nullptr, BDb, 0);
  k_gather<128,true,false><<<dim3(NN/4), B, 0, stream>>>(rp_v, cv, csr_v, invv,
                                                         BDb, nullptr, BCb, 1);
  // ---- GCN layer 2 ----
  k_gemm_mfma<128,64><<<dim3(NB), B, 0, stream>>>(BBb, gW2t, nullptr, dinv, BAb, 0);
  k_gather<64,false,true><<<dim3(NN/4), B, 0, stream>>>(rp_g, cg, csr_g, dinv,
                                                        BAb, gb2f, x2f, 0);
  // ---- HGNNP layer 2 ----
  k_gemm_mfma<128,64><<<dim3(NB), B, 0, stream>>>(BCb, hW2t, hb2f, nullptr, BAb, 0);
  k_gather<64,true,false><<<dim3(NEH/4), B, 0, stream>>>(rp_e, ce, csr_e, inve,
                                                         BAb, nullptr, BDb, 0);
  k_gather<64,false,false><<<dim3(NN/4), B, 0, stream>>>(rp_v, cv, csr_v, invv,
                                                         BDb, nullptr, x4f, 0);

  // ---- embeds + normalized rows -> dataf ----
  k_embeds<<<dim3((NN+3)/4), B, 0, stream>>>(x2f, x4f, d_out, dataf, dflg);

  // ---- clustering (coalesced tiles) ----
  k_mu_init<<<dim3(3), B, 0, stream>>>(dataf, mu);
  for (int it = 0; it < 4; ++it){   // gated by iter < *num_iter (setup: 1)
    k_cluster_iter<<<dim3(CBLK), dim3(640), 0, stream>>>(dataf, mu, part, pcr, nit, it);
    k_cred1       <<<dim3(40),   dim3(768), 0, stream>>>(part, pcr, p2, pc2, nit, it);
    k_cred2       <<<dim3(1),    dim3(768), 0, stream>>>(p2, pc2, csum, cr, nit, it);
    k_mu_update   <<<dim3(1),    dim3(640), 0, stream>>>(mu, csum, cr, nit, it);
  }
  k_cluster_final<<<dim3(CBLK), dim3(640), 0, stream>>>(dataf, mu, d_out, dflg);
  k_mu_out       <<<dim3(3),  B, 0, stream>>>(mu, d_out, dflg);
}

// Round 16
// 321.269 us; speedup vs baseline: 1.1844x; 1.1587x over previous
//
#include <hip/hip_runtime.h>
#include <hip/hip_bf16.h>

// HGNNP_GCN + ClusterNet forward, MI355X (round 16).
// R15: no single kernel >40us; 44 launches -> dispatch overhead + serialization
// is now a first-order cost. This round: launch fusion 44->28. prep fused;
// CSR hist/fillA/fillB fused across structures (invs folded into fillB);
// GEMM||gather phase fusion (disjoint pipes co-resident, BEb breaks the BAb
// WAR hazard); cluster reduce chain 4->3 launches/iter; mu_out into final.

#define NN   50000
#define NP   50048   // padded rows (782 * 64)
#define EE   800000
#define NINC 200000
#define NEH  10000
#define KCL  10
#define CBLK 782     // ceil(NN/64)

#define MU_OFF  0
#define R_OFF   640
#define EMB_OFF 500640
#define D_OFF   3700640

typedef __hip_bfloat16 bf16;
typedef unsigned short u16;
typedef unsigned int   u32;
typedef __attribute__((ext_vector_type(8))) short short8;
typedef __attribute__((ext_vector_type(4))) float f32x4;

__device__ __forceinline__ float b2f(bf16 v){ return __bfloat162float(v); }
__device__ __forceinline__ float us2f(u16 u){ return __uint_as_float(((unsigned)u) << 16); }
__device__ __forceinline__ u16 f2bu(float f){
  unsigned u = __float_as_uint(f);
  return (u16)((u + 0x7fffu + ((u >> 16) & 1u)) >> 16);   // RNE
}
__device__ __forceinline__ bf16 f2b(float f){
  u16 r = f2bu(f);
  bf16 h;
  reinterpret_cast<u16&>(h) = r;
  return h;
}
__device__ __forceinline__ float ldf(const void* p, size_t i, int isbf){
  return isbf ? b2f(((const bf16*)p)[i]) : ((const float*)p)[i];
}
__device__ __forceinline__ void stf(void* p, size_t i, float v, int isbf){
  if (isbf) ((bf16*)p)[i] = f2b(v);
  else      ((float*)p)[i] = v;
}

// ---------------- dtype detector ----------------
__global__ void k_detect(const u16* __restrict__ xr, int* flag){
  __shared__ int bad;
  if (threadIdx.x == 0) bad = 0;
  __syncthreads();
  for (int i = threadIdx.x; i < 4096; i += 256){
    int e = (xr[i] >> 7) & 0xFF;
    if (e >= 0xEF) bad = 1;
  }
  __syncthreads();
  if (threadIdx.x == 0) *flag = bad ? 0 : 1;   // 1 = bf16, 0 = f32
}

// ---------------- fused input prep: aconv (12500 blocks) + wprep (128) ----------------
__global__ __launch_bounds__(256) void k_prep(const void* __restrict__ x, u16* __restrict__ xb,
    const void* gW1, const void* hW1, const void* gW2, const void* hW2,
    const void* gb1, const void* hb1, const void* gb2, const void* hb2,
    u16* gW1t, u16* hW1t, u16* gW2t, u16* hW2t,
    float* gb1f, float* hb1f, float* gb2f, float* hb2f,
    const int* __restrict__ flag){
  const int isbf = flag[0];
  const int blk = blockIdx.x;
  if (blk < 12500){
    int i = blk*256 + threadIdx.x;           // exactly covers NN*256/4
    ushort4 o;
    if (isbf){
      o = ((const ushort4*)x)[i];
    } else {
      float4 v = ((const float4*)x)[i];
      o = make_ushort4(f2bu(v.x), f2bu(v.y), f2bu(v.z), f2bu(v.w));
    }
    ((ushort4*)xb)[i] = o;
  } else {
    int i = (blk - 12500)*256 + threadIdx.x;
    if (i < 256*128){
      int n = i >> 8, k = i & 255;
      gW1t[i] = f2bu(ldf(gW1, (size_t)k*128 + n, isbf));
      hW1t[i] = f2bu(ldf(hW1, (size_t)k*128 + n, isbf));
    }
    if (i < 64*128){
      int n = i >> 7, k = i & 127;
      gW2t[i] = f2bu(ldf(gW2, (size_t)k*64 + n, isbf));
      hW2t[i] = f2bu(ldf(hW2, (size_t)k*64 + n, isbf));
    }
    if (i < 128){ gb1f[i] = ldf(gb1,i,isbf); hb1f[i] = ldf(hb1,i,isbf); }
    if (i < 64) { gb2f[i] = ldf(gb2,i,isbf); hb2f[i] = ldf(hb2,i,isbf); }
  }
}

// ---------------- fused CSR build ----------------
// hist: blocks 0..127 gcn, 128..191 hv, 192..255 he
__global__ __launch_bounds__(256) void k_hist_all(const int* __restrict__ dstp,
    const int* __restrict__ hv, const int* __restrict__ he,
    int* HAg, int* HAv, int* HAe){
  __shared__ u32 hist[250];
  const int blk = blockIdx.x;
  const int* key; int* HA; int chunk, npb, lb;
  if (blk < 128){ key=dstp; HA=HAg; chunk=6250; npb=200; lb=blk; }
  else if (blk < 192){ key=hv; HA=HAv; chunk=3125; npb=200; lb=blk-128; }
  else { key=he; HA=HAe; chunk=3125; npb=40; lb=blk-192; }
  for (int i = threadIdx.x; i < 250; i += 256) hist[i] = 0;
  __syncthreads();
  int base = lb*chunk;
  for (int i = threadIdx.x; i < chunk; i += 256)
    atomicAdd(&hist[key[base+i]/npb], 1u);
  __syncthreads();
  int* out = HA + lb*250;
  for (int i = threadIdx.x; i < 250; i += 256) out[i] = (int)hist[i];
}

// per-bucket prefix over chunks + bucket starts (3 blocks)
__global__ void k_scanA_all(int* HAg, int* HAv, int* HAe,
                            int* bsg, int* bsv, int* bse){
  int* HA; int* bs; int nch;
  if (blockIdx.x == 0){ HA = HAg; bs = bsg; nch = 128; }
  else if (blockIdx.x == 1){ HA = HAv; bs = bsv; nch = 64; }
  else { HA = HAe; bs = bse; nch = 64; }
  __shared__ int s[256];
  int t = threadIdx.x;
  int run = 0;
  if (t < 250){
    for (int c = 0; c < nch; ++c){
      int v = HA[c*250 + t];
      HA[c*250 + t] = run;
      run += v;
    }
  }
  int own = (t < 250) ? run : 0;
  s[t] = own; __syncthreads();
  #pragma unroll
  for (int off = 1; off < 256; off <<= 1){
    int add = (t >= off) ? s[t-off] : 0;
    __syncthreads();
    s[t] += add;
    __syncthreads();
  }
  if (t < 250) bs[t] = s[t] - own;
  if (t == 255) bs[250] = s[255];
}

// fillA fused: same block split as hist
__global__ __launch_bounds__(256) void k_fillA_all(const int* __restrict__ dstp,
    const int* __restrict__ srcp, const int* __restrict__ hv, const int* __restrict__ he,
    const int* HAg, const int* HAv, const int* HAe,
    const int* bsg, const int* bsv, const int* bse,
    u32* pg, u32* pv, u32* pe){
  __shared__ u32 cur[250];
  const int blk = blockIdx.x;
  const int* key; const int* val; const int* HA; const int* bs; u32* packed;
  int chunk, npb, lb;
  if (blk < 128){ key=dstp; val=srcp; HA=HAg; bs=bsg; packed=pg; chunk=6250; npb=200; lb=blk; }
  else if (blk < 192){ key=hv; val=he; HA=HAv; bs=bsv; packed=pv; chunk=3125; npb=200; lb=blk-128; }
  else { key=he; val=hv; HA=HAe; bs=bse; packed=pe; chunk=3125; npb=40; lb=blk-192; }
  const int* pre = HA + lb*250;
  for (int i = threadIdx.x; i < 250; i += 256) cur[i] = (u32)(bs[i] + pre[i]);
  __syncthreads();
  int base = lb*chunk;
  for (int i = threadIdx.x; i < chunk; i += 256){
    int k = key[base+i];
    int b = k / npb;
    u32 pos = atomicAdd(&cur[b], 1u);
    packed[pos] = ((u32)(k - b*npb) << 16) | (u32)val[base+i];
  }
}

// fillB fused (750 blocks) + inv computations folded in
__global__ __launch_bounds__(256) void k_fillB_all(
    const u32* pg, const u32* pv, const u32* pe,
    const int* bsg, const int* bsv, const int* bse,
    int* csr_g, int* csr_v, int* csr_e,
    int* cg, int* cv, int* ce, int* rp_g, int* rp_v, int* rp_e,
    float* dinv, float* invv, float* inve){
  __shared__ u32 hist[200];
  __shared__ int s[256];
  __shared__ u32 cur[200];
  const int blk = blockIdx.x;
  const u32* packed; const int* bs; int* csr; int* cnt; int* rp; int npb, b, mode;
  if (blk < 250){ packed=pg; bs=bsg; csr=csr_g; cnt=cg; rp=rp_g; npb=200; b=blk; mode=0; }
  else if (blk < 500){ packed=pv; bs=bsv; csr=csr_v; cnt=cv; rp=rp_v; npb=200; b=blk-250; mode=1; }
  else { packed=pe; bs=bse; csr=csr_e; cnt=ce; rp=rp_e; npb=40; b=blk-500; mode=2; }
  const int s0 = bs[b], m = bs[b+1] - s0;
  const int t = threadIdx.x;
  for (int i = t; i < npb; i += 256) hist[i] = 0;
  __syncthreads();
  for (int i = t; i < m; i += 256)
    atomicAdd(&hist[packed[s0+i] >> 16], 1u);
  __syncthreads();
  int own = (t < npb) ? (int)hist[t] : 0;
  s[t] = own; __syncthreads();
  #pragma unroll
  for (int off = 1; off < 256; off <<= 1){
    int add = (t >= off) ? s[t-off] : 0;
    __syncthreads();
    s[t] += add;
    __syncthreads();
  }
  if (t < npb){
    int excl = s[t] - own;
    int node = b*npb + t;
    cnt[node] = own;
    rp[node]  = s0 + excl;
    cur[t] = (u32)(s0 + excl);
    if (mode == 0)      dinv[node] = rsqrtf(1.0f + (float)own);
    else if (mode == 1) invv[node] = 1.0f / fmaxf((float)own, 1.0f);
    else                inve[node] = 1.0f / fmaxf((float)own, 1.0f);
  }
  if (mode == 0 && b == 249 && t < NP - NN) dinv[NN + t] = 0.f;  // pad rows
  __syncthreads();
  for (int i = t; i < m; i += 256){
    u32 p = packed[s0+i];
    u32 pos = atomicAdd(&cur[p >> 16], 1u);
    csr[pos] = (int)(p & 0xffffu);
  }
}

// ---------------- MFMA GEMM body ----------------
template<int KDIM, int NCOL>
__device__ __forceinline__ void gemm_body(const u16* __restrict__ A,
    const u16* __restrict__ Wt, const float* __restrict__ bias,
    const float* __restrict__ rowscale, u16* __restrict__ C, int relu, int bid)
{
  constexpr int NT  = NCOL/16;
  constexpr int LDA = 40;
  __shared__ __align__(16) u16 Asl[64][LDA];
  __shared__ __align__(16) u16 Wsl[NCOL][LDA];
  const int tid  = threadIdx.x;
  const int wave = tid >> 6, lane = tid & 63;
  const int l15 = lane & 15, l4 = lane >> 4;
  const int row0 = bid * 64;
  const int ar = tid >> 2, aq = tid & 3;
  constexpr int NW = NCOL*4/256;

  f32x4 acc[NT] = {};

  for (int kk = 0; kk < KDIM; kk += 32){
    {
      uint4 v = *(const uint4*)(A + (size_t)(row0 + ar)*KDIM + kk + aq*8);
      *(uint4*)&Asl[ar][aq*8] = v;
    }
    #pragma unroll
    for (int w2 = 0; w2 < NW; ++w2){
      int c = tid + w2*256;
      int n = c >> 2, q = c & 3;
      uint4 v = *(const uint4*)(Wt + (size_t)n*KDIM + kk + q*8);
      *(uint4*)&Wsl[n][q*8] = v;
    }
    __syncthreads();
    short8 af = *(const short8*)&Asl[wave*16 + l15][l4*8];
    #pragma unroll
    for (int t = 0; t < NT; ++t){
      short8 bf = *(const short8*)&Wsl[t*16 + l15][l4*8];
      acc[t] = __builtin_amdgcn_mfma_f32_16x16x32_bf16(af, bf, acc[t], 0, 0, 0);
    }
    __syncthreads();
  }

  #pragma unroll
  for (int t = 0; t < NT; ++t){
    int gcol = t*16 + l15;
    float b = bias ? bias[gcol] : 0.f;
    #pragma unroll
    for (int e = 0; e < 4; ++e){
      int grow = row0 + wave*16 + l4*4 + e;
      float v = acc[t][e] + b;
      if (relu) v = fmaxf(v, 0.f);
      if (rowscale) v *= rowscale[grow];
      C[(size_t)grow*NCOL + gcol] = f2bu(v);
    }
  }
}

// ---------------- gather body: one wave per dst row, 4 rows/block ----------------
template<int F, bool OUTBF, bool SELF>
__device__ __forceinline__ void gather_body(const int* __restrict__ rp,
    const int* __restrict__ cnt, const int* __restrict__ csr,
    const float* __restrict__ scale, const u16* __restrict__ h,
    const float* __restrict__ bias, void* __restrict__ out, int relu, int bid)
{
  const int wave = threadIdx.x >> 6, lane = threadIdx.x & 63;
  const int d = bid*4 + wave;
  const int k0 = rp[d], n = cnt[d];

  if constexpr (F == 128){
    const uint* h32 = (const uint*)h;
    float a0=0,a1=0,b0=0,b1=0,c0=0,c1=0,e0=0,e1=0;
    if (SELF){
      uint v = h32[(size_t)d*64 + lane];
      a0 = us2f((u16)v); a1 = us2f((u16)(v>>16));
    }
    for (int base = 0; base < n; base += 64){
      int mm = n - base; if (mm > 64) mm = 64;
      int idx = (lane < mm) ? csr[k0 + base + lane] : 0;
      int jj = 0;
      for (; jj + 4 <= mm; jj += 4){
        int s0=__shfl(idx,jj), s1=__shfl(idx,jj+1), s2=__shfl(idx,jj+2), s3=__shfl(idx,jj+3);
        uint v0 = h32[(size_t)s0*64 + lane];
        uint v1 = h32[(size_t)s1*64 + lane];
        uint v2 = h32[(size_t)s2*64 + lane];
        uint v3 = h32[(size_t)s3*64 + lane];
        a0 += us2f((u16)v0); a1 += us2f((u16)(v0>>16));
        b0 += us2f((u16)v1); b1 += us2f((u16)(v1>>16));
        c0 += us2f((u16)v2); c1 += us2f((u16)(v2>>16));
        e0 += us2f((u16)v3); e1 += us2f((u16)(v3>>16));
      }
      for (; jj < mm; ++jj){
        int s = __shfl(idx, jj);
        uint v = h32[(size_t)s*64 + lane];
        a0 += us2f((u16)v); a1 += us2f((u16)(v>>16));
      }
    }
    float sc = scale[d];
    float o0 = ((a0+b0)+(c0+e0))*sc;
    float o1 = ((a1+b1)+(c1+e1))*sc;
    if (bias){ o0 += bias[lane*2]; o1 += bias[lane*2+1]; }
    if (relu){ o0 = fmaxf(o0,0.f); o1 = fmaxf(o1,0.f); }
    if (OUTBF){
      ((uint*)out)[(size_t)d*64 + lane] = (uint)f2bu(o0) | ((uint)f2bu(o1) << 16);
    } else {
      ((float2*)out)[(size_t)d*64 + lane] = make_float2(o0, o1);
    }
  } else { // F == 64
    float a=0,b=0,c=0,e=0;
    if (SELF) a = us2f(h[(size_t)d*64 + lane]);
    for (int base = 0; base < n; base += 64){
      int mm = n - base; if (mm > 64) mm = 64;
      int idx = (lane < mm) ? csr[k0 + base + lane] : 0;
      int jj = 0;
      for (; jj + 4 <= mm; jj += 4){
        int s0=__shfl(idx,jj), s1=__shfl(idx,jj+1), s2=__shfl(idx,jj+2), s3=__shfl(idx,jj+3);
        a += us2f(h[(size_t)s0*64 + lane]);
        b += us2f(h[(size_t)s1*64 + lane]);
        c += us2f(h[(size_t)s2*64 + lane]);
        e += us2f(h[(size_t)s3*64 + lane]);
      }
      for (; jj < mm; ++jj){
        int s = __shfl(idx, jj);
        a += us2f(h[(size_t)s*64 + lane]);
      }
    }
    float o = ((a+b)+(c+e))*scale[d];
    if (bias) o += bias[lane];
    if (relu) o = fmaxf(o, 0.f);
    if (OUTBF) ((u16*)out)[(size_t)d*64 + lane] = f2bu(o);
    else       ((float*)out)[(size_t)d*64 + lane] = o;
  }
}

// ---------------- phase kernels ----------------
__global__ __launch_bounds__(256) void k_pA(const u16* xb, const u16* gW1t,
    const float* dinv, u16* BAb){
  gemm_body<256,128>(xb, gW1t, nullptr, dinv, BAb, 0, blockIdx.x);
}
// GEMM_h1 (782) || gather_gcn1 (12500)
__global__ __launch_bounds__(256) void k_pB(const u16* xb, const u16* hW1t,
    const float* hb1f, u16* BEb,
    const int* rp_g, const int* cg, const int* csr_g, const float* dinv,
    const u16* BAb, const float* gb1f, u16* BBb){
  if (blockIdx.x < 782) gemm_body<256,128>(xb, hW1t, hb1f, nullptr, BEb, 0, blockIdx.x);
  else gather_body<128,true,true>(rp_g, cg, csr_g, dinv, BAb, gb1f, BBb, 1, blockIdx.x - 782);
}
// GEMM_g2 (782) || gather_e1 (2500)
__global__ __launch_bounds__(256) void k_pC(const u16* BBb, const u16* gW2t,
    const float* dinv, u16* BAb,
    const int* rp_e, const int* ce, const int* csr_e, const float* inve,
    const u16* BEb, u16* BDb){
  if (blockIdx.x < 782) gemm_body<128,64>(BBb, gW2t, nullptr, dinv, BAb, 0, blockIdx.x);
  else gather_body<128,true,false>(rp_e, ce, csr_e, inve, BEb, nullptr, BDb, 0, blockIdx.x - 782);
}
// gather_v1 (12500) || gather_gcn2 (12500)
__global__ __launch_bounds__(256) void k_pD(
    const int* rp_v, const int* cv, const int* csr_v, const float* invv,
    const u16* BDb, u16* BCb,
    const int* rp_g, const int* cg, const int* csr_g, const float* dinv,
    const u16* BAb, const float* gb2f, float* x2f){
  if (blockIdx.x < 12500) gather_body<128,true,false>(rp_v, cv, csr_v, invv, BDb, nullptr, BCb, 1, blockIdx.x);
  else gather_body<64,false,true>(rp_g, cg, csr_g, dinv, BAb, gb2f, x2f, 0, blockIdx.x - 12500);
}
__global__ __launch_bounds__(256) void k_pE(const u16* BCb, const u16* hW2t,
    const float* hb2f, u16* BEb){
  gemm_body<128,64>(BCb, hW2t, hb2f, nullptr, BEb, 0, blockIdx.x);
}
__global__ __launch_bounds__(256) void k_pF(const int* rp_e, const int* ce,
    const int* csr_e, const float* inve, const u16* BEb, u16* BDb){
  gather_body<64,true,false>(rp_e, ce, csr_e, inve, BEb, nullptr, BDb, 0, blockIdx.x);
}
__global__ __launch_bounds__(256) void k_pG(const int* rp_v, const int* cv,
    const int* csr_v, const float* invv, const u16* BDb, float* x4f){
  gather_body<64,false,false>(rp_v, cv, csr_v, invv, BDb, nullptr, x4f, 0, blockIdx.x);
}

// ---------------- embeds + row normalize ----------------
__global__ void k_embeds(const float* __restrict__ x2, const float* __restrict__ x4,
                         void* __restrict__ out, float* __restrict__ data,
                         const int* __restrict__ flag){
  int row  = blockIdx.x*4 + (threadIdx.x >> 6);
  int lane = threadIdx.x & 63;
  if (row >= NN) return;
  size_t idx = (size_t)row*64 + lane;
  float v = 0.5f*(x2[idx] + x4[idx]);
  float ss = v*v;
  #pragma unroll
  for (int off=32; off>0; off>>=1) ss += __shfl_xor(ss, off);
  float inv = rsqrtf(ss);
  data[idx] = v*inv;
  stf(out, EMB_OFF + idx, v, flag[0]);
}

// ---------------- clustering ----------------
__global__ void k_mu_init(const float* __restrict__ data, float* __restrict__ mu){
  int p = threadIdx.x;      // 640 threads, 1 block
  int k = p >> 6, f = p & 63;
  mu[p] = data[(size_t)k*(NN/KCL)*64 + f];
}

__global__ __launch_bounds__(640) void k_cluster_iter(const float* __restrict__ data,
    const float* __restrict__ mu, float* __restrict__ part, float* __restrict__ pcr,
    const int* __restrict__ nit, int iter)
{
  if (iter >= nit[0]) return;
  __shared__ float ms[640];
  __shared__ float dt[64][65];
  __shared__ float ds[64][11];
  const int tid = threadIdx.x;
  ms[tid] = mu[tid];
  const int base = blockIdx.x*64;
  for (int i = tid; i < 4096; i += 640){
    int r = i >> 6, f = i & 63;
    int grow = base + r;
    dt[r][f] = (grow < NN) ? data[(size_t)grow*64 + f] : 0.f;
  }
  __syncthreads();
  {
    const int row = tid & 63, k = tid >> 6;
    float dot = 0.f;
    #pragma unroll 16
    for (int f = 0; f < 64; ++f)
      dot = fmaf(dt[row][f], ms[k*64 + f], dot);
    ds[row][k] = dot;
  }
  __syncthreads();
  if (tid < 64){
    float dot[KCL];
    #pragma unroll
    for (int k = 0; k < KCL; ++k) dot[k] = ds[tid][k];
    float m = -1e30f;
    #pragma unroll
    for (int k = 0; k < KCL; ++k) m = fmaxf(m, 5.0f*dot[k]);
    float s = 0.f, ev[KCL];
    #pragma unroll
    for (int k = 0; k < KCL; ++k){ ev[k] = expf(5.0f*dot[k]-m); s += ev[k]; }
    float inv = (base + tid < NN) ? 1.0f/s : 0.f;
    #pragma unroll
    for (int k = 0; k < KCL; ++k) ds[tid][k] = ev[k]*inv;
  }
  __syncthreads();
  {
    const int f = tid & 63, k = tid >> 6;
    float acc = 0.f, crp = 0.f;
    #pragma unroll 8
    for (int t = 0; t < 64; ++t){
      float rv = ds[t][k];
      acc = fmaf(rv, dt[t][f], acc);
      crp += rv;
    }
    part[(size_t)blockIdx.x*640 + tid] = acc;
    if (f == 0) pcr[blockIdx.x*16 + k] = crp;
  }
}

__global__ void k_cred1(const float* __restrict__ part, const float* __restrict__ pcr,
                        float* __restrict__ p2, float* __restrict__ pc2,
                        const int* __restrict__ nit, int iter){
  if (iter >= nit[0]) return;
  int b = blockIdx.x, t = threadIdx.x;
  int r0 = b*20, r1 = r0 + 20; if (r1 > CBLK) r1 = CBLK;
  if (t < 640){
    float a = 0.f;
    for (int r = r0; r < r1; ++r) a += part[(size_t)r*640 + t];
    p2[(size_t)b*640 + t] = a;
  } else if (t < 640 + KCL){
    int k = t - 640;
    float a = 0.f;
    for (int r = r0; r < r1; ++r) a += pcr[r*16 + k];
    pc2[b*16 + k] = a;
  }
}

// cred2 + mu_update fused (1 block, 768 threads)
__global__ void k_cred2mu(const float* __restrict__ p2, const float* __restrict__ pc2,
                          float* __restrict__ mu, const int* __restrict__ nit, int iter){
  if (iter >= nit[0]) return;
  __shared__ float crs[16];
  int t = threadIdx.x;
  if (t >= 640 && t < 640 + KCL){
    int k = t - 640;
    float a = 0.f;
    #pragma unroll
    for (int b = 0; b < 40; ++b) a += pc2[b*16 + k];
    crs[k] = a;
  }
  __syncthreads();
  if (t < 640){
    float a = 0.f;
    #pragma unroll
    for (int b = 0; b < 40; ++b) a += p2[(size_t)b*640 + t];
    mu[t] = a / crs[t >> 6];
  }
}

// final (+ mu_out in block 0)
__global__ __launch_bounds__(640) void k_cluster_final(const float* __restrict__ data,
    const float* __restrict__ mu, void* __restrict__ out, const int* __restrict__ flag)
{
  __shared__ float ms[640];
  __shared__ float dt[64][65];
  __shared__ float ds[64][11];
  const int tid = threadIdx.x;
  ms[tid] = mu[tid];
  const int base = blockIdx.x*64;
  for (int i = tid; i < 4096; i += 640){
    int r = i >> 6, f = i & 63;
    int grow = base + r;
    dt[r][f] = (grow < NN) ? data[(size_t)grow*64 + f] : 0.f;
  }
  __syncthreads();
  {
    const int row = tid & 63, k = tid >> 6;
    float dot = 0.f;
    #pragma unroll 16
    for (int f = 0; f < 64; ++f)
      dot = fmaf(dt[row][f], ms[k*64 + f], dot);
    ds[row][k] = dot;
  }
  __syncthreads();
  const int isbf = flag[0];
  if (blockIdx.x == 0) stf(out, MU_OFF + tid, ms[tid], isbf);   // mu_out fused
  if (tid < 64 && base + tid < NN){
    const int row = base + tid;
    float dot[KCL];
    #pragma unroll
    for (int k = 0; k < KCL; ++k) dot[k] = ds[tid][k];
    float m = -1e30f;
    #pragma unroll
    for (int k = 0; k < KCL; ++k) m = fmaxf(m, 5.0f*dot[k]);
    float s = 0.f, ev[KCL];
    #pragma unroll
    for (int k = 0; k < KCL; ++k){ ev[k] = expf(5.0f*dot[k]-m); s += ev[k]; }
    float inv = 1.0f/s;
    #pragma unroll
    for (int k = 0; k < KCL; ++k){
      stf(out, (size_t)D_OFF + (size_t)row*KCL + k, dot[k],    isbf);
      stf(out, (size_t)R_OFF + (size_t)row*KCL + k, ev[k]*inv, isbf);
    }
  }
}

// ---------------- launch ----------------
extern "C" void kernel_launch(void* const* d_in, const int* in_sizes, int n_in,
                              void* d_out, int out_size, void* d_ws, size_t ws_size,
                              hipStream_t stream)
{
  const void* x   = d_in[0];
  const int*  ei  = (const int*)d_in[1];
  const int*  hv  = (const int*)d_in[2];
  const int*  he  = (const int*)d_in[3];
  const void* gW1 = d_in[4];
  const void* gb1 = d_in[5];
  const void* gW2 = d_in[6];
  const void* gb2 = d_in[7];
  const void* hW1 = d_in[8];
  const void* hb1 = d_in[9];
  const void* hW2 = d_in[10];
  const void* hb2 = d_in[11];
  const int*  nit = (const int*)d_in[12];

  float* ws = (float*)d_ws;
  size_t o = 0;
  u16*   xb  = (u16*)(ws + o); o += (size_t)NP*128;   // x bf16 NP x 256
  u16*   BAb = (u16*)(ws + o); o += (size_t)NP*64;
  u16*   BBb = (u16*)(ws + o); o += (size_t)NP*64;
  u16*   BCb = (u16*)(ws + o); o += (size_t)NP*64;
  u16*   BEb = (u16*)(ws + o); o += (size_t)NP*64;    // second GEMM-out buffer
  u16*   BDb = (u16*)(ws + o); o += (size_t)NEH*64;
  u16*  gW1t = (u16*)(ws + o); o += 16384;
  u16*  hW1t = (u16*)(ws + o); o += 16384;
  u16*  gW2t = (u16*)(ws + o); o += 4096;
  u16*  hW2t = (u16*)(ws + o); o += 4096;
  float* gb1f = ws + o; o += 128;
  float* hb1f = ws + o; o += 128;
  float* gb2f = ws + o; o += 64;
  float* hb2f = ws + o; o += 64;
  float* dinv = ws + o; o += 50048;
  float* invv = ws + o; o += 50048;
  float* inve = ws + o; o += 10048;
  float* mu   = ws + o; o += 640;
  float* part = ws + o; o += (size_t)CBLK*640;
  float* pcr  = ws + o; o += CBLK*16;
  float* p2   = ws + o; o += 40*640;
  float* pc2  = ws + o; o += 40*16;
  int*   dflg = (int*)(ws + o); o += 16;
  float* x2f   = (float*)xb;
  float* x4f   = (float*)xb + (size_t)NP*64;
  float* dataf = (float*)BBb;
  // int region (CSR)
  int* ib = (int*)(ws + o);
  size_t io = 0;
  int* cg    = ib + io; io += NN;
  int* cv    = ib + io; io += NN;
  int* ce    = ib + io; io += NEH + 48;
  int* rp_g  = ib + io; io += NN;
  int* rp_v  = ib + io; io += NN;
  int* rp_e  = ib + io; io += NEH + 48;
  int* csr_g = ib + io; io += EE;
  int* csr_e = ib + io; io += NINC;
  int* csr_v = ib + io; io += NINC;
  int* HAg   = ib + io; io += 128*250;
  int* HAv   = ib + io; io += 64*250;
  int* HAe   = ib + io; io += 64*250;
  int* bsg   = ib + io; io += 256;
  int* bsv   = ib + io; io += 256;
  int* bse   = ib + io; io += 256;
  u32* pg = (u32*)(ib + io); io += EE;
  u32* pv = (u32*)(ib + io); io += NINC;
  u32* pe = (u32*)(ib + io); io += NINC;

  const int* srcp = ei;
  const int* dstp = ei + EE;
  dim3 B(256);

  // dtype detection + fused prep
  k_detect<<<dim3(1), B, 0, stream>>>((const u16*)x, dflg);
  k_prep<<<dim3(12628), B, 0, stream>>>(x, xb, gW1, hW1, gW2, hW2,
                                        gb1, hb1, gb2, hb2,
                                        gW1t, hW1t, gW2t, hW2t,
                                        gb1f, hb1f, gb2f, hb2f, dflg);

  // fused CSR build
  k_hist_all <<<dim3(256), B, 0, stream>>>(dstp, hv, he, HAg, HAv, HAe);
  k_scanA_all<<<dim3(3),   B, 0, stream>>>(HAg, HAv, HAe, bsg, bsv, bse);
  k_fillA_all<<<dim3(256), B, 0, stream>>>(dstp, srcp, hv, he, HAg, HAv, HAe,
                                           bsg, bsv, bse, pg, pv, pe);
  k_fillB_all<<<dim3(750), B, 0, stream>>>(pg, pv, pe, bsg, bsv, bse,
                                           csr_g, csr_v, csr_e, cg, cv, ce,
                                           rp_g, rp_v, rp_e, dinv, invv, inve);

  // fused GEMM/gather phases
  k_pA<<<dim3(782),   B, 0, stream>>>(xb, gW1t, dinv, BAb);
  k_pB<<<dim3(13282), B, 0, stream>>>(xb, hW1t, hb1f, BEb,
                                      rp_g, cg, csr_g, dinv, BAb, gb1f, BBb);
  k_pC<<<dim3(3282),  B, 0, stream>>>(BBb, gW2t, dinv, BAb,
                                      rp_e, ce, csr_e, inve, BEb, BDb);
  k_pD<<<dim3(25000), B, 0, stream>>>(rp_v, cv, csr_v, invv, BDb, BCb,
                                      rp_g, cg, csr_g, dinv, BAb, gb2f, x2f);
  k_pE<<<dim3(782),   B, 0, stream>>>(BCb, hW2t, hb2f, BEb);
  k_pF<<<dim3(2500),  B, 0, stream>>>(rp_e, ce, csr_e, inve, BEb, BDb);
  k_pG<<<dim3(12500), B, 0, stream>>>(rp_v, cv, csr_v, invv, BDb, x4f);

  // embeds + normalized rows -> dataf
  k_embeds<<<dim3((NN+3)/4), B, 0, stream>>>(x2f, x4f, d_out, dataf, dflg);

  // clustering
  k_mu_init<<<dim3(1), dim3(640), 0, stream>>>(dataf, mu);
  for (int it = 0; it < 4; ++it){   // gated by iter < *num_iter (setup: 1)
    k_cluster_iter<<<dim3(CBLK), dim3(640), 0, stream>>>(dataf, mu, part, pcr, nit, it);
    k_cred1       <<<dim3(40),   dim3(768), 0, stream>>>(part, pcr, p2, pc2, nit, it);
    k_cred2mu     <<<dim3(1),    dim3(768), 0, stream>>>(p2, pc2, mu, nit, it);
  }
  k_cluster_final<<<dim3(CBLK), dim3(640), 0, stream>>>(dataf, mu, d_out, dflg);
}